// Round 11
// baseline (987.389 us; speedup 1.0000x reference)
//
#include <hip/hip_runtime.h>
#include <cmath>

#define NTOK 577
#define NB 32
#define NC 768
#define NH 12
#define HD 64
#define SP1 257
#define XTOK 18464   // 32*577
#define MOUT 8224    // 32*257

typedef __attribute__((ext_vector_type(8))) short short8;
typedef __attribute__((ext_vector_type(4))) float floatx4;
typedef __attribute__((ext_vector_type(4))) double doublex4;

union S8 { short s[8]; short8 v; };
union S4 { short s[4]; unsigned long long u; };

__device__ __forceinline__ short f2bf(float f) {
  union { float f; unsigned u; } v; v.f = f;
  unsigned r = v.u + 0x7fffu + ((v.u >> 16) & 1u);   // RNE
  return (short)(r >> 16);
}

// ---- body: one-shot fp32 -> bf16 conversion (virtual block vb) -----------
__device__ __forceinline__ void tobf3_body(const float* __restrict__ x,
                                           const float* __restrict__ w,
                                           const float* __restrict__ pw,
                                           short* __restrict__ xbf,
                                           short* __restrict__ wbf,
                                           short* __restrict__ wpbf, int vb) {
  const size_t NX = 1772544, NW = 147456;
  size_t t = (size_t)vb * 256 + threadIdx.x;
  const float* s; short* d; size_t off;
  if (t < NX)           { s = x;  d = xbf;  off = t * 8; }
  else if (t < NX + NW) { s = w;  d = wbf;  off = (t - NX) * 8; }
  else                  { s = pw; d = wpbf; off = (t - NX - NW) * 8; }
  float4 v0 = *(const float4*)(s + off);
  float4 v1 = *(const float4*)(s + off + 4);
  S8 p;
  p.s[0] = f2bf(v0.x); p.s[1] = f2bf(v0.y);
  p.s[2] = f2bf(v0.z); p.s[3] = f2bf(v0.w);
  p.s[4] = f2bf(v1.x); p.s[5] = f2bf(v1.y);
  p.s[6] = f2bf(v1.z); p.s[7] = f2bf(v1.w);
  *(short8*)(d + off) = p.v;
}

// ---- body: fp64 MFMA V projection + exact vnorm2 (R9/R10 437us version) --
// Flat LDS pointers: Xs stride 132 (8448B), Ws stride 68 (4352B).
__device__ __forceinline__ void vnorm_body(const float* __restrict__ x,
                                           const float* __restrict__ w,
                                           short* __restrict__ Vb,
                                           double* __restrict__ vnorm2,
                                           float* Xs, float* Ws,
                                           int h, int my) {
  const int tid = threadIdx.x;
  const int lane = tid & 63, wv = tid >> 6;
  const int li = lane & 15, quad = lane >> 4;
  const int mBase = my * 128;
  const int rowb = wv * 32;              // wave's 32-row slice of the tile
  const int arow = tid >> 1, ak = (tid & 1) * 8;
  const int wrow = tid >> 2, wk = (tid & 3) * 4;
  int am = mBase + arow; if (am >= XTOK) am = 0;
  const float* aptr = x + (size_t)am * NC + ak;
  const float* bptr = w + (size_t)(1536 + h * HD + wrow) * NC + wk;

  // prologue: load tile 0 into registers
  float4 xa = *(const float4*)(aptr);
  float4 xb = *(const float4*)(aptr + 4);
  float4 wb = *(const float4*)(bptr);

  doublex4 acc[2][4] = {};
  for (int kt = 0; kt < NC; kt += 16) {
    Xs[(ak + 0) * 132 + arow] = xa.x; Xs[(ak + 1) * 132 + arow] = xa.y;
    Xs[(ak + 2) * 132 + arow] = xa.z; Xs[(ak + 3) * 132 + arow] = xa.w;
    Xs[(ak + 4) * 132 + arow] = xb.x; Xs[(ak + 5) * 132 + arow] = xb.y;
    Xs[(ak + 6) * 132 + arow] = xb.z; Xs[(ak + 7) * 132 + arow] = xb.w;
    Ws[(wk + 0) * 68 + wrow] = wb.x; Ws[(wk + 1) * 68 + wrow] = wb.y;
    Ws[(wk + 2) * 68 + wrow] = wb.z; Ws[(wk + 3) * 68 + wrow] = wb.w;
    __syncthreads();
    if (kt + 16 < NC) {              // prefetch next tile
      xa = *(const float4*)(aptr + kt + 16);
      xb = *(const float4*)(aptr + kt + 20);
      wb = *(const float4*)(bptr + kt + 16);
    }
    #pragma unroll
    for (int k4 = 0; k4 < 4; ++k4) {
      const int kk = k4 * 4 + quad;      // A/B operand: k = lane>>4
      double a0 = (double)Xs[kk * 132 + rowb + li];
      double a1 = (double)Xs[kk * 132 + rowb + 16 + li];
      double b0 = (double)Ws[kk * 68 + li];
      double b1 = (double)Ws[kk * 68 + 16 + li];
      double b2 = (double)Ws[kk * 68 + 32 + li];
      double b3 = (double)Ws[kk * 68 + 48 + li];
      acc[0][0] = __builtin_amdgcn_mfma_f64_16x16x4f64(a0, b0, acc[0][0], 0, 0, 0);
      acc[0][1] = __builtin_amdgcn_mfma_f64_16x16x4f64(a0, b1, acc[0][1], 0, 0, 0);
      acc[0][2] = __builtin_amdgcn_mfma_f64_16x16x4f64(a0, b2, acc[0][2], 0, 0, 0);
      acc[0][3] = __builtin_amdgcn_mfma_f64_16x16x4f64(a0, b3, acc[0][3], 0, 0, 0);
      acc[1][0] = __builtin_amdgcn_mfma_f64_16x16x4f64(a1, b0, acc[1][0], 0, 0, 0);
      acc[1][1] = __builtin_amdgcn_mfma_f64_16x16x4f64(a1, b1, acc[1][1], 0, 0, 0);
      acc[1][2] = __builtin_amdgcn_mfma_f64_16x16x4f64(a1, b2, acc[1][2], 0, 0, 0);
      acc[1][3] = __builtin_amdgcn_mfma_f64_16x16x4f64(a1, b3, acc[1][3], 0, 0, 0);
    }
    __syncthreads();
  }
  // epilogue: C/D layout row = quad*4 + r (+16g), col = c*16 + li.
  #pragma unroll
  for (int g = 0; g < 2; ++g) {
    #pragma unroll
    for (int r = 0; r < 4; ++r) {
      int m = mBase + rowb + g * 16 + quad * 4 + r;
      double s = acc[g][0][r] * acc[g][0][r] + acc[g][1][r] * acc[g][1][r] +
                 acc[g][2][r] * acc[g][2][r] + acc[g][3][r] * acc[g][3][r];
      s += __shfl_xor(s, 1);
      s += __shfl_xor(s, 2);
      s += __shfl_xor(s, 4);
      s += __shfl_xor(s, 8);
      if (m < XTOK) {
        int bb = m / NTOK, jt = m % NTOK;
        short* vrow = &Vb[(((size_t)(bb * NH + h)) * NTOK + jt) * HD];
        #pragma unroll
        for (int c = 0; c < 4; ++c)
          vrow[c * 16 + li] = f2bf((float)acc[g][c][r]);
        if (li == 0)
          vnorm2[((size_t)(bb * NH + h)) * NTOK + jt] = s;
      }
    }
  }
}

// ---- body: merged fp64 q0 + wq0 for one (b,h) ----------------------------
__device__ __forceinline__ void qwq_body(const float* __restrict__ x,
                                         const float* __restrict__ w,
                                         double* __restrict__ wq0,
                                         float* xs, double* q0s, int bh) {
  const int b = bh / NH, h = bh % NH;
  const int tid = threadIdx.x;
  for (int c = tid; c < NC; c += 256) xs[c] = x[(size_t)b * NTOK * NC + c];
  __syncthreads();
  {
    const int e = tid >> 2, p = tid & 3;
    const float* wr = w + (size_t)(h * HD + e) * NC + p * 192;
    double a = 0.0;
    for (int c = 0; c < 192; ++c)
      a += (double)xs[p * 192 + c] * (double)wr[c];
    double a1 = __shfl_down(a, 1);
    double a2 = __shfl_down(a, 2);
    double a3 = __shfl_down(a, 3);
    if (p == 0) q0s[e] = ((a + a1) + a2) + a3;
  }
  __syncthreads();
  for (int c = tid; c < NC; c += 256) {
    double acc = 0.0;
    #pragma unroll
    for (int e = 0; e < HD; ++e)
      acc += q0s[e] * (double)w[(size_t)(768 + h * HD + e) * NC + c];
    wq0[(size_t)bh * NC + c] = acc;
  }
}

// ===== merged launch: vnorm (1740) + tobf3 (7788) + qwq (384) = 9912 ======
// vnorm blocks first (long; start ASAP); tobf3/qwq backfill CU slots during
// vnorm's residency. Union LDS = 12800B = vnorm's own; union VGPR ~= vnorm's
// -> vnorm occupancy unchanged (unlike R8's failed kv-merge). Bodies are
// byte-identical to the standalone kernels -> outputs bit-identical.
__global__ __launch_bounds__(256) void k_pre(const float* __restrict__ x,
                                             const float* __restrict__ qw,
                                             const float* __restrict__ pw,
                                             short* __restrict__ xbf,
                                             short* __restrict__ wbf,
                                             short* __restrict__ wpbf,
                                             short* __restrict__ Vb,
                                             double* __restrict__ vnorm2,
                                             double* __restrict__ wq0) {
  __shared__ __align__(16) char smem[12800];
  const int bx = blockIdx.x;
  if (bx < 1740) {
    vnorm_body(x, qw, Vb, vnorm2, (float*)smem, (float*)(smem + 8448),
               bx % NH, bx / NH);
  } else if (bx < 1740 + 7788) {
    tobf3_body(x, qw, pw, xbf, wbf, wpbf, bx - 1740);
  } else {
    qwq_body(x, qw, wq0, (float*)smem, (double*)(smem + 3072), bx - 9528);
  }
}

// MFMA loop with PRE-CONVERTED bf16 operands: staging is pure short8 copies.
// C[m,n] = sum_c A[m,c]*B[n,c], fp32 acc. 128x128 tile, 4 waves, 24 k-steps.
__device__ __forceinline__ void mfma_loop_bf(const short* aptr, const short* bptr,
                                             short* As, short* Bs, int srow,
                                             int scol, int wm, int wn, int quad,
                                             int l16, floatx4 acc[4][4]) {
  for (int kt = 0; kt < NC; kt += 32) {
    short8 a0 = *(const short8*)(aptr + kt);
    short8 a1 = *(const short8*)(aptr + kt + 8);
    short8 b0 = *(const short8*)(bptr + kt);
    short8 b1 = *(const short8*)(bptr + kt + 8);
    *(short8*)&As[srow * 40 + scol] = a0;
    *(short8*)&As[srow * 40 + scol + 8] = a1;
    *(short8*)&Bs[srow * 40 + scol] = b0;
    *(short8*)&Bs[srow * 40 + scol + 8] = b1;
    __syncthreads();
    short8 af[4], bf[4];
    #pragma unroll
    for (int g = 0; g < 4; ++g) {
      af[g] = *(const short8*)&As[(wm + g * 16 + l16) * 40 + quad * 8];
      bf[g] = *(const short8*)&Bs[(wn + g * 16 + l16) * 40 + quad * 8];
    }
    #pragma unroll
    for (int gm = 0; gm < 4; ++gm)
      #pragma unroll
      for (int gn = 0; gn < 4; ++gn)
        acc[gm][gn] = __builtin_amdgcn_mfma_f32_16x16x32_bf16(
            af[gm], bf[gn], acc[gm][gn], 0, 0, 0);
    __syncthreads();
  }
}

// ============ K projection (bf16 in/out): Kb[b,h,j,e] bf16 ===============
__global__ __launch_bounds__(256) void k_kv_bf(const short* __restrict__ xbf,
                                               const short* __restrict__ wbf,
                                               short* __restrict__ Kb) {
  __shared__ __align__(16) short As[128 * 40];
  __shared__ __align__(16) short Bs[128 * 40];
  const int tid = threadIdx.x;
  const int lane = tid & 63, wv = tid >> 6;
  const int quad = lane >> 4, l16 = lane & 15;
  const int wm = (wv >> 1) * 64, wn = (wv & 1) * 64;
  const int mBase = blockIdx.y * 128, nBase = blockIdx.x * 128;
  const int srow = tid >> 1, scol = (tid & 1) * 16;
  int am = mBase + srow; if (am >= XTOK) am = 0;
  const short* aptr = xbf + (size_t)am * NC + scol;
  const short* bptr = wbf + (size_t)(768 + nBase + srow) * NC + scol;
  floatx4 acc[4][4] = {};
  mfma_loop_bf(aptr, bptr, As, Bs, srow, scol, wm, wn, quad, l16, acc);
  #pragma unroll
  for (int gm = 0; gm < 4; ++gm) {
    #pragma unroll
    for (int gn = 0; gn < 4; ++gn) {
      #pragma unroll
      for (int r = 0; r < 4; ++r) {
        int m = mBase + wm + gm * 16 + quad * 4 + r;
        if (m >= XTOK) continue;
        int n = nBase + wn + gn * 16 + l16;
        int bb = m / NTOK, jt = m % NTOK;
        int hh = n >> 6, e = n & 63;
        Kb[(((size_t)(bb * NH + hh)) * NTOK + jt) * HD + e] = f2bf(acc[gm][gn][r]);
      }
    }
  }
}

// ============ gathered Q projection (bf16 in/out): Qs[m,n] bf16 ==========
__global__ __launch_bounds__(256) void k_qs_bf(const short* __restrict__ xbf,
                                               const short* __restrict__ wbf,
                                               const int* __restrict__ uniq,
                                               short* __restrict__ Qs) {
  __shared__ __align__(16) short As[128 * 40];
  __shared__ __align__(16) short Bs[128 * 40];
  const int tid = threadIdx.x;
  const int lane = tid & 63, wv = tid >> 6;
  const int quad = lane >> 4, l16 = lane & 15;
  const int wm = (wv >> 1) * 64, wn = (wv & 1) * 64;
  const int mBase = blockIdx.y * 128, nBase = blockIdx.x * 128;
  const int srow = tid >> 1, scol = (tid & 1) * 16;
  int am = mBase + srow;
  const short* aptr;
  if (am < MOUT) {
    int bb = am / SP1, ii = am % SP1;
    int tok = uniq[bb * SP1 + ii];
    aptr = xbf + ((size_t)bb * NTOK + tok) * NC + scol;
  } else {
    aptr = xbf + scol;
  }
  const short* bptr = wbf + (size_t)(nBase + srow) * NC + scol;
  floatx4 acc[4][4] = {};
  mfma_loop_bf(aptr, bptr, As, Bs, srow, scol, wm, wn, quad, l16, acc);
  #pragma unroll
  for (int gm = 0; gm < 4; ++gm) {
    #pragma unroll
    for (int gn = 0; gn < 4; ++gn) {
      #pragma unroll
      for (int r = 0; r < 4; ++r) {
        int m = mBase + wm + gm * 16 + quad * 4 + r;
        if (m >= MOUT) continue;
        int n = nBase + wn + gn * 16 + l16;
        Qs[(size_t)m * NC + n] = f2bf(acc[gm][gn][r]);
      }
    }
  }
}

// ============ output projection + bias (bf16 in, fp32 out) ===============
__global__ __launch_bounds__(256) void k_proj_bf(const short* __restrict__ A,
                                                 const short* __restrict__ wpbf,
                                                 const float* __restrict__ bias,
                                                 float* __restrict__ out) {
  __shared__ __align__(16) short As[128 * 40];
  __shared__ __align__(16) short Bs[128 * 40];
  const int tid = threadIdx.x;
  const int lane = tid & 63, wv = tid >> 6;
  const int quad = lane >> 4, l16 = lane & 15;
  const int wm = (wv >> 1) * 64, wn = (wv & 1) * 64;
  const int mBase = blockIdx.y * 128, nBase = blockIdx.x * 128;
  const int srow = tid >> 1, scol = (tid & 1) * 16;
  int am = mBase + srow; if (am >= MOUT) am = 0;
  const short* aptr = A + (size_t)am * NC + scol;
  const short* bptr = wpbf + (size_t)(nBase + srow) * NC + scol;
  floatx4 acc[4][4] = {};
  mfma_loop_bf(aptr, bptr, As, Bs, srow, scol, wm, wn, quad, l16, acc);
  #pragma unroll
  for (int gm = 0; gm < 4; ++gm) {
    #pragma unroll
    for (int gn = 0; gn < 4; ++gn) {
      #pragma unroll
      for (int r = 0; r < 4; ++r) {
        int m = mBase + wm + gm * 16 + quad * 4 + r;
        if (m >= MOUT) continue;
        int n = nBase + wn + gn * 16 + l16;
        out[(size_t)m * NC + n] = acc[gm][gn][r] + bias[n];
      }
    }
  }
}

// ------- fp64 tiled: logits0[b,h,j] = 0.125 * x[b,j,:].wq0[b,h,:] ---------
__global__ __launch_bounds__(256) void k_logits0b(const float* __restrict__ x,
                                                  const double* __restrict__ wq0,
                                                  double* __restrict__ logits0) {
  const int jt = blockIdx.x;
  const int b = blockIdx.y;
  const int tid = threadIdx.x;
  __shared__ float xs[64][129];
  __shared__ double ws[12][128];
  const int j = tid & 63;
  const int hg = tid >> 6;
  double acc[3] = {0.0, 0.0, 0.0};
  for (int ct = 0; ct < 6; ++ct) {
    const int r = tid >> 2, cg = (tid & 3) * 32;
    int jg = jt * 64 + r; if (jg > 576) jg = 576;
    const float* xr = x + ((size_t)b * NTOK + jg) * NC + ct * 128 + cg;
    #pragma unroll
    for (int k = 0; k < 32; k += 4) {
      float4 v = *(const float4*)(xr + k);
      xs[r][cg + k + 0] = v.x; xs[r][cg + k + 1] = v.y;
      xs[r][cg + k + 2] = v.z; xs[r][cg + k + 3] = v.w;
    }
    for (int t = tid; t < 12 * 128; t += 256) {
      int hh = t >> 7, cc = t & 127;
      ws[hh][cc] = wq0[((size_t)b * NH + hh) * NC + ct * 128 + cc];
    }
    __syncthreads();
    #pragma unroll 4
    for (int c = 0; c < 128; ++c) {
      double xv = (double)xs[j][c];
      acc[0] += xv * ws[hg * 3 + 0][c];
      acc[1] += xv * ws[hg * 3 + 1][c];
      acc[2] += xv * ws[hg * 3 + 2][c];
    }
    __syncthreads();
  }
  const int jg = jt * 64 + j;
  if (jg < NTOK) {
    #pragma unroll
    for (int k = 0; k < 3; ++k)
      logits0[((size_t)b * NH + (hg * 3 + k)) * NTOK + jg] = 0.125 * acc[k];
  }
}

// ===== per-(b,h) significance contribution (12x parallel) ================
__global__ __launch_bounds__(256) void k_sigh(const double* __restrict__ logits0,
                                              const double* __restrict__ vnorm2,
                                              double* __restrict__ contrib) {
  const int bh = blockIdx.x;
  const int tid = threadIdx.x;
  __shared__ double sred[256];
  const double* lp = logits0 + (size_t)bh * NTOK;
  const double* vn = vnorm2 + (size_t)bh * NTOK;
  double pmax = -1e300;
  for (int j = tid; j < NTOK; j += 256) pmax = fmax(pmax, lp[j]);
  sred[tid] = pmax;
  __syncthreads();
  for (int s = 128; s > 0; s >>= 1) {
    if (tid < s) sred[tid] = fmax(sred[tid], sred[tid + s]);
    __syncthreads();
  }
  double m = sred[0];
  __syncthreads();
  double psum = 0.0;
  for (int j = tid; j < NTOK; j += 256) psum += exp(lp[j] - m);
  sred[tid] = psum;
  __syncthreads();
  for (int s = 128; s > 0; s >>= 1) {
    if (tid < s) sred[tid] += sred[tid + s];
    __syncthreads();
  }
  double denom = sred[0];
  __syncthreads();
  for (int j = tid + 1; j < NTOK; j += 256)
    contrib[(size_t)bh * 576 + (j - 1)] = exp(lp[j] - m) / denom * sqrt(vn[j]);
}

// ---- combine contributions + cdf + sampling + unique (outputs 1,2) -------
__global__ __launch_bounds__(256) void k_sig2(const double* __restrict__ contrib,
                                              int* __restrict__ uniq_ws,
                                              float* __restrict__ out_mask,
                                              float* __restrict__ out_uniq) {
  const int b = blockIdx.x;
  const int tid = threadIdx.x;
  __shared__ double sig[576];
  __shared__ double cdf[576];
  __shared__ double sred[256];
  __shared__ int ids[256];
  __shared__ int flags[NTOK];
  __shared__ int ulist[SP1];
  for (int j = tid; j < 576; j += 256) {
    double s = 0.0;
    #pragma unroll
    for (int h = 0; h < NH; ++h)
      s += contrib[((size_t)(b * NH + h)) * 576 + j];
    sig[j] = s;
  }
  __syncthreads();
  double tsum = 0.0;
  for (int j = tid; j < 576; j += 256) tsum += sig[j];
  sred[tid] = tsum;
  __syncthreads();
  for (int s = 128; s > 0; s >>= 1) {
    if (tid < s) sred[tid] += sred[tid + s];
    __syncthreads();
  }
  double denom2 = sred[0] + 1e-6;
  __syncthreads();
  if (tid == 0) {
    double c = 0.0;
    for (int j = 0; j < 576; ++j) { c += sig[j] / denom2; cdf[j] = c; }
  }
  __syncthreads();
  {
    double step = (2.0 * tid + 1.0) / 512.0;
    double best = 1e300;
    int bj = 0;
    for (int j = 0; j < 576; ++j) {
      double d = fabs(step - cdf[j]);
      if (d < best) { best = d; bj = j; }
    }
    ids[tid] = bj + 1;
  }
  for (int j = tid; j < NTOK; j += 256) flags[j] = 0;
  __syncthreads();
  flags[ids[tid]] = 1;
  __syncthreads();
  if (tid == 0) {
    int cnt = 0;
    ulist[0] = 0;
    for (int j = 1; j < NTOK; ++j)
      if (flags[j]) ulist[++cnt] = j;
    for (int k = cnt + 1; k < SP1; ++k) ulist[k] = 0;
  }
  __syncthreads();
  for (int k = tid; k < SP1; k += 256) {
    int v = ulist[k];
    uniq_ws[b * SP1 + k] = v;
    out_uniq[b * SP1 + k] = (float)v;
    out_mask[b * SP1 + k] = (k == 0 || v != 0) ? 1.0f : 0.0f;
  }
}

// -------- flash-style attention over sampled rows, bf16 MFMA ----------
__global__ __launch_bounds__(256) void k_attn2(const short* __restrict__ Qs,
                                               const short* __restrict__ Kb,
                                               const short* __restrict__ Vb,
                                               short* __restrict__ attnv) {
  const int it = blockIdx.x;
  const int h = blockIdx.y;
  const int b = blockIdx.z;
  const int tid = threadIdx.x;
  const int lane = tid & 63, wv = tid >> 6;
  const int l16 = lane & 15, quad = lane >> 4;
  const int i0 = it * 64;
  __shared__ __align__(16) short Qt[64][72];   // [i][e]
  __shared__ __align__(16) short Kt[64][72];   // [j][e]
  __shared__ __align__(16) short Vt[64][72];   // [e][j]  (transposed)
  __shared__ __align__(16) short Pt[64][72];   // [i][j]
  {
    const int r16 = tid & 15;
    const int e = (tid >> 4) * 4;
    #pragma unroll
    for (int rb = 0; rb < 4; ++rb) {
      int row = rb * 16 + r16;
      int ig = i0 + row; if (ig > 256) ig = 256;
      *(unsigned long long*)&Qt[row][e] =
          *(const unsigned long long*)(Qs + ((size_t)b * SP1 + ig) * NC + h * HD + e);
    }
  }
  float m_i[4], l_i[4];
  floatx4 O[4];
  #pragma unroll
  for (int r = 0; r < 4; ++r) { m_i[r] = -1e30f; l_i[r] = 0.f; }
  #pragma unroll
  for (int g = 0; g < 4; ++g) O[g] = (floatx4){0.f, 0.f, 0.f, 0.f};
  const short* Kh = Kb + ((size_t)(b * NH + h)) * NTOK * HD;
  const short* Vh = Vb + ((size_t)(b * NH + h)) * NTOK * HD;
  const int prow = wv * 16 + l16;            // A-operand row for this lane
  for (int jt = 0; jt < 10; ++jt) {
    {
      const int r16 = tid & 15;
      const int e = (tid >> 4) * 4;
      #pragma unroll
      for (int rb = 0; rb < 4; ++rb) {
        int jr = rb * 16 + r16;
        int jg = jt * 64 + jr; if (jg > 576) jg = 576;
        *(unsigned long long*)&Kt[jr][e] =
            *(const unsigned long long*)(Kh + (size_t)jg * HD + e);
        S4 vv; vv.u = *(const unsigned long long*)(Vh + (size_t)jg * HD + e);
        Vt[e + 0][jr] = vv.s[0]; Vt[e + 1][jr] = vv.s[1];
        Vt[e + 2][jr] = vv.s[2]; Vt[e + 3][jr] = vv.s[3];
      }
    }
    __syncthreads();
    floatx4 s[4];
    #pragma unroll
    for (int g = 0; g < 4; ++g) s[g] = (floatx4){0.f, 0.f, 0.f, 0.f};
    {
      short8 aq0 = *(const short8*)&Qt[prow][quad * 8];
      short8 aq1 = *(const short8*)&Qt[prow][32 + quad * 8];
      #pragma unroll
      for (int g = 0; g < 4; ++g) {
        short8 bk0 = *(const short8*)&Kt[g * 16 + l16][quad * 8];
        short8 bk1 = *(const short8*)&Kt[g * 16 + l16][32 + quad * 8];
        s[g] = __builtin_amdgcn_mfma_f32_16x16x32_bf16(aq0, bk0, s[g], 0, 0, 0);
        s[g] = __builtin_amdgcn_mfma_f32_16x16x32_bf16(aq1, bk1, s[g], 0, 0, 0);
      }
    }
    #pragma unroll
    for (int g = 0; g < 4; ++g) {
      int jg = jt * 64 + g * 16 + l16;
      #pragma unroll
      for (int r = 0; r < 4; ++r) {
        float sv = s[g][r] * 0.125f;
        s[g][r] = (jg >= NTOK) ? -1e30f : sv;
      }
    }
    #pragma unroll
    for (int r = 0; r < 4; ++r) {
      float mr = fmaxf(fmaxf(s[0][r], s[1][r]), fmaxf(s[2][r], s[3][r]));
      #pragma unroll
      for (int off = 1; off < 16; off <<= 1) mr = fmaxf(mr, __shfl_xor(mr, off));
      float mn = fmaxf(m_i[r], mr);
      float alpha = expf(m_i[r] - mn);
      float ps = 0.f;
      #pragma unroll
      for (int g = 0; g < 4; ++g) {
        float p = expf(s[g][r] - mn);
        s[g][r] = p;
        ps += p;
      }
      #pragma unroll
      for (int off = 1; off < 16; off <<= 1) ps += __shfl_xor(ps, off);
      l_i[r] = l_i[r] * alpha + ps;
      m_i[r] = mn;
      #pragma unroll
      for (int g = 0; g < 4; ++g) O[g][r] *= alpha;
    }
    #pragma unroll
    for (int g = 0; g < 4; ++g)
      #pragma unroll
      for (int r = 0; r < 4; ++r)
        Pt[wv * 16 + quad * 4 + r][g * 16 + l16] = f2bf(s[g][r]);
    __syncthreads();
    {
      short8 ap0 = *(const short8*)&Pt[prow][quad * 8];
      short8 ap1 = *(const short8*)&Pt[prow][32 + quad * 8];
      #pragma unroll
      for (int g = 0; g < 4; ++g) {
        short8 bv0 = *(const short8*)&Vt[g * 16 + l16][quad * 8];
        short8 bv1 = *(const short8*)&Vt[g * 16 + l16][32 + quad * 8];
        O[g] = __builtin_amdgcn_mfma_f32_16x16x32_bf16(ap0, bv0, O[g], 0, 0, 0);
        O[g] = __builtin_amdgcn_mfma_f32_16x16x32_bf16(ap1, bv1, O[g], 0, 0, 0);
      }
    }
    __syncthreads();
  }
  #pragma unroll
  for (int r = 0; r < 4; ++r) {
    int i = i0 + wv * 16 + quad * 4 + r;
    if (i >= SP1) continue;
    float inv = 1.0f / l_i[r];
    #pragma unroll
    for (int g = 0; g < 4; ++g)
      attnv[((size_t)b * SP1 + i) * NC + h * HD + g * 16 + l16] = f2bf(O[g][r] * inv);
  }
}

extern "C" void kernel_launch(void* const* d_in, const int* in_sizes, int n_in,
                              void* d_out, int out_size, void* d_ws,
                              size_t ws_size, hipStream_t stream) {
  (void)in_sizes; (void)n_in; (void)out_size; (void)ws_size;
  const float* x = (const float*)d_in[0];
  const float* qkv_w = (const float*)d_in[2];
  const float* proj_w = (const float*)d_in[3];
  const float* proj_b = (const float*)d_in[4];

  char* ws = (char*)d_ws;
  size_t off = 0;
  short* xbf = (short*)(ws + off); off += (size_t)XTOK * NC * 2;
  short* wbf = (short*)(ws + off); off += (size_t)1536 * NC * 2;
  short* wpbf = (short*)(ws + off); off += (size_t)NC * NC * 2;
  short* Kb = (short*)(ws + off); off += (size_t)NB * NH * NTOK * HD * 2;
  short* Vb = (short*)(ws + off); off += (size_t)NB * NH * NTOK * HD * 2;
  short* Qs = (short*)(ws + off); off += (size_t)MOUT * NC * 2;
  short* attnv = (short*)(ws + off); off += (size_t)MOUT * NC * 2;
  double* wq0 = (double*)(ws + off); off += (size_t)NB * NH * NC * 8;
  double* logits0 = (double*)(ws + off); off += (size_t)NB * NH * NTOK * 8;
  double* vnorm2 = (double*)(ws + off); off += (size_t)NB * NH * NTOK * 8;
  double* contrib = (double*)(ws + off); off += (size_t)NB * NH * 576 * 8;
  int* uniq_ws = (int*)(ws + off); off += (size_t)NB * SP1 * 4;

  float* out0 = (float*)d_out;
  float* out_mask = out0 + (size_t)MOUT * NC;
  float* out_uniq = out_mask + (size_t)NB * SP1;

  // 1. merged: V projection/vnorm2 (fp64 MFMA) + bf16 conversion + q0/wq0.
  //    All three mutually independent; tobf3/qwq hide under vnorm's 437us.
  k_pre<<<9912, 256, 0, stream>>>(x, qkv_w, proj_w, xbf, wbf, wpbf,
                                  Vb, vnorm2, wq0);
  // 2. CLS logits (fp64, tiled)
  k_logits0b<<<dim3(10, NB), 256, 0, stream>>>(x, wq0, logits0);
  // 3. K projection (bf16 in/out)
  k_kv_bf<<<dim3(6, 145), 256, 0, stream>>>(xbf, wbf, Kb);
  // 4. per-(b,h) significance contributions (12x parallel)
  k_sigh<<<NB * NH, 256, 0, stream>>>(logits0, vnorm2, contrib);
  // 5. combine + cdf + sampling + unique (+ outputs 1,2)
  k_sig2<<<NB, 256, 0, stream>>>(contrib, uniq_ws, out_mask, out_uniq);
  // 6. gathered Q projection (bf16 in/out)
  k_qs_bf<<<dim3(6, 65), 256, 0, stream>>>(xbf, wbf, uniq_ws, Qs);
  // 7. flash-style attention over sampled rows (all-bf16 staging)
  k_attn2<<<dim3(5, NH, NB), 256, 0, stream>>>(Qs, Kb, Vb, attnv);
  // 8. output projection (+bias, bf16 in, fp32 out) -> output 0
  k_proj_bf<<<dim3(6, 65), 256, 0, stream>>>(attnv, wpbf, proj_b, out0);
}

// Round 12
// 813.922 us; speedup vs baseline: 1.2131x; 1.2131x over previous
//
#include <hip/hip_runtime.h>
#include <cmath>

#define NTOK 577
#define NB 32
#define NC 768
#define NH 12
#define HD 64
#define SP1 257
#define XTOK 18464   // 32*577
#define MOUT 8224    // 32*257

typedef __attribute__((ext_vector_type(8))) short short8;
typedef __attribute__((ext_vector_type(4))) float floatx4;
typedef __attribute__((ext_vector_type(4))) double doublex4;

union S8 { short s[8]; short8 v; };
union S4 { short s[4]; unsigned long long u; };

__device__ __forceinline__ short f2bf(float f) {
  union { float f; unsigned u; } v; v.f = f;
  unsigned r = v.u + 0x7fffu + ((v.u >> 16) & 1u);   // RNE
  return (short)(r >> 16);
}

// ---- body: one-shot fp32 -> bf16 conversion (virtual block vb) -----------
__device__ __forceinline__ void tobf3_body(const float* __restrict__ x,
                                           const float* __restrict__ w,
                                           const float* __restrict__ pw,
                                           short* __restrict__ xbf,
                                           short* __restrict__ wbf,
                                           short* __restrict__ wpbf, int vb) {
  const size_t NX = 1772544, NW = 147456;
  size_t t = (size_t)vb * 256 + threadIdx.x;
  const float* s; short* d; size_t off;
  if (t < NX)           { s = x;  d = xbf;  off = t * 8; }
  else if (t < NX + NW) { s = w;  d = wbf;  off = (t - NX) * 8; }
  else                  { s = pw; d = wpbf; off = (t - NX - NW) * 8; }
  float4 v0 = *(const float4*)(s + off);
  float4 v1 = *(const float4*)(s + off + 4);
  S8 p;
  p.s[0] = f2bf(v0.x); p.s[1] = f2bf(v0.y);
  p.s[2] = f2bf(v0.z); p.s[3] = f2bf(v0.w);
  p.s[4] = f2bf(v1.x); p.s[5] = f2bf(v1.y);
  p.s[6] = f2bf(v1.z); p.s[7] = f2bf(v1.w);
  *(short8*)(d + off) = p.v;
}

// ---- body: fp64 MFMA V projection + exact vnorm2 (R9/R10 437us version) --
// Flat LDS pointers: Xs stride 132 (8448B), Ws stride 68 (4352B).
__device__ __forceinline__ void vnorm_body(const float* __restrict__ x,
                                           const float* __restrict__ w,
                                           short* __restrict__ Vb,
                                           double* __restrict__ vnorm2,
                                           float* Xs, float* Ws,
                                           int h, int my) {
  const int tid = threadIdx.x;
  const int lane = tid & 63, wv = tid >> 6;
  const int li = lane & 15, quad = lane >> 4;
  const int mBase = my * 128;
  const int rowb = wv * 32;              // wave's 32-row slice of the tile
  const int arow = tid >> 1, ak = (tid & 1) * 8;
  const int wrow = tid >> 2, wk = (tid & 3) * 4;
  int am = mBase + arow; if (am >= XTOK) am = 0;
  const float* aptr = x + (size_t)am * NC + ak;
  const float* bptr = w + (size_t)(1536 + h * HD + wrow) * NC + wk;

  // prologue: load tile 0 into registers
  float4 xa = *(const float4*)(aptr);
  float4 xb = *(const float4*)(aptr + 4);
  float4 wb = *(const float4*)(bptr);

  doublex4 acc[2][4] = {};
  for (int kt = 0; kt < NC; kt += 16) {
    Xs[(ak + 0) * 132 + arow] = xa.x; Xs[(ak + 1) * 132 + arow] = xa.y;
    Xs[(ak + 2) * 132 + arow] = xa.z; Xs[(ak + 3) * 132 + arow] = xa.w;
    Xs[(ak + 4) * 132 + arow] = xb.x; Xs[(ak + 5) * 132 + arow] = xb.y;
    Xs[(ak + 6) * 132 + arow] = xb.z; Xs[(ak + 7) * 132 + arow] = xb.w;
    Ws[(wk + 0) * 68 + wrow] = wb.x; Ws[(wk + 1) * 68 + wrow] = wb.y;
    Ws[(wk + 2) * 68 + wrow] = wb.z; Ws[(wk + 3) * 68 + wrow] = wb.w;
    __syncthreads();
    if (kt + 16 < NC) {              // prefetch next tile
      xa = *(const float4*)(aptr + kt + 16);
      xb = *(const float4*)(aptr + kt + 20);
      wb = *(const float4*)(bptr + kt + 16);
    }
    #pragma unroll
    for (int k4 = 0; k4 < 4; ++k4) {
      const int kk = k4 * 4 + quad;      // A/B operand: k = lane>>4
      double a0 = (double)Xs[kk * 132 + rowb + li];
      double a1 = (double)Xs[kk * 132 + rowb + 16 + li];
      double b0 = (double)Ws[kk * 68 + li];
      double b1 = (double)Ws[kk * 68 + 16 + li];
      double b2 = (double)Ws[kk * 68 + 32 + li];
      double b3 = (double)Ws[kk * 68 + 48 + li];
      acc[0][0] = __builtin_amdgcn_mfma_f64_16x16x4f64(a0, b0, acc[0][0], 0, 0, 0);
      acc[0][1] = __builtin_amdgcn_mfma_f64_16x16x4f64(a0, b1, acc[0][1], 0, 0, 0);
      acc[0][2] = __builtin_amdgcn_mfma_f64_16x16x4f64(a0, b2, acc[0][2], 0, 0, 0);
      acc[0][3] = __builtin_amdgcn_mfma_f64_16x16x4f64(a0, b3, acc[0][3], 0, 0, 0);
      acc[1][0] = __builtin_amdgcn_mfma_f64_16x16x4f64(a1, b0, acc[1][0], 0, 0, 0);
      acc[1][1] = __builtin_amdgcn_mfma_f64_16x16x4f64(a1, b1, acc[1][1], 0, 0, 0);
      acc[1][2] = __builtin_amdgcn_mfma_f64_16x16x4f64(a1, b2, acc[1][2], 0, 0, 0);
      acc[1][3] = __builtin_amdgcn_mfma_f64_16x16x4f64(a1, b3, acc[1][3], 0, 0, 0);
    }
    __syncthreads();
  }
  // epilogue: C/D layout row = quad*4 + r (+16g), col = c*16 + li.
  #pragma unroll
  for (int g = 0; g < 2; ++g) {
    #pragma unroll
    for (int r = 0; r < 4; ++r) {
      int m = mBase + rowb + g * 16 + quad * 4 + r;
      double s = acc[g][0][r] * acc[g][0][r] + acc[g][1][r] * acc[g][1][r] +
                 acc[g][2][r] * acc[g][2][r] + acc[g][3][r] * acc[g][3][r];
      s += __shfl_xor(s, 1);
      s += __shfl_xor(s, 2);
      s += __shfl_xor(s, 4);
      s += __shfl_xor(s, 8);
      if (m < XTOK) {
        int bb = m / NTOK, jt = m % NTOK;
        short* vrow = &Vb[(((size_t)(bb * NH + h)) * NTOK + jt) * HD];
        #pragma unroll
        for (int c = 0; c < 4; ++c)
          vrow[c * 16 + li] = f2bf((float)acc[g][c][r]);
        if (li == 0)
          vnorm2[((size_t)(bb * NH + h)) * NTOK + jt] = s;
      }
    }
  }
}

// ---- body: merged fp64 q0 + wq0 for one (b,h) ----------------------------
__device__ __forceinline__ void qwq_body(const float* __restrict__ x,
                                         const float* __restrict__ w,
                                         double* __restrict__ wq0,
                                         float* xs, double* q0s, int bh) {
  const int b = bh / NH, h = bh % NH;
  const int tid = threadIdx.x;
  for (int c = tid; c < NC; c += 256) xs[c] = x[(size_t)b * NTOK * NC + c];
  __syncthreads();
  {
    const int e = tid >> 2, p = tid & 3;
    const float* wr = w + (size_t)(h * HD + e) * NC + p * 192;
    double a = 0.0;
    for (int c = 0; c < 192; ++c)
      a += (double)xs[p * 192 + c] * (double)wr[c];
    double a1 = __shfl_down(a, 1);
    double a2 = __shfl_down(a, 2);
    double a3 = __shfl_down(a, 3);
    if (p == 0) q0s[e] = ((a + a1) + a2) + a3;
  }
  __syncthreads();
  for (int c = tid; c < NC; c += 256) {
    double acc = 0.0;
    #pragma unroll
    for (int e = 0; e < HD; ++e)
      acc += q0s[e] * (double)w[(size_t)(768 + h * HD + e) * NC + c];
    wq0[(size_t)bh * NC + c] = acc;
  }
}

// ===== merged launch: vnorm (1740) + tobf3 (7788) + qwq (384) = 9912 ======
// __launch_bounds__(256, 4): min 4 waves/EU -> regalloc capped at 128 VGPR.
// R11's regression was the merged kernel's 136-VGPR allocation (max over
// branches) dropping vnorm's occupancy; vnorm's body needs only 84, so the
// cap is free for it and at worst spills a little in the tiny qwq body.
// Bodies byte-identical to R10's standalone kernels -> outputs bit-identical.
__global__ __launch_bounds__(256, 4) void k_pre(const float* __restrict__ x,
                                                const float* __restrict__ qw,
                                                const float* __restrict__ pw,
                                                short* __restrict__ xbf,
                                                short* __restrict__ wbf,
                                                short* __restrict__ wpbf,
                                                short* __restrict__ Vb,
                                                double* __restrict__ vnorm2,
                                                double* __restrict__ wq0) {
  __shared__ __align__(16) char smem[12800];
  const int bx = blockIdx.x;
  if (bx < 1740) {
    vnorm_body(x, qw, Vb, vnorm2, (float*)smem, (float*)(smem + 8448),
               bx % NH, bx / NH);
  } else if (bx < 1740 + 7788) {
    tobf3_body(x, qw, pw, xbf, wbf, wpbf, bx - 1740);
  } else {
    qwq_body(x, qw, wq0, (float*)smem, (double*)(smem + 3072), bx - 9528);
  }
}

// MFMA loop with PRE-CONVERTED bf16 operands: staging is pure short8 copies.
// C[m,n] = sum_c A[m,c]*B[n,c], fp32 acc. 128x128 tile, 4 waves, 24 k-steps.
__device__ __forceinline__ void mfma_loop_bf(const short* aptr, const short* bptr,
                                             short* As, short* Bs, int srow,
                                             int scol, int wm, int wn, int quad,
                                             int l16, floatx4 acc[4][4]) {
  for (int kt = 0; kt < NC; kt += 32) {
    short8 a0 = *(const short8*)(aptr + kt);
    short8 a1 = *(const short8*)(aptr + kt + 8);
    short8 b0 = *(const short8*)(bptr + kt);
    short8 b1 = *(const short8*)(bptr + kt + 8);
    *(short8*)&As[srow * 40 + scol] = a0;
    *(short8*)&As[srow * 40 + scol + 8] = a1;
    *(short8*)&Bs[srow * 40 + scol] = b0;
    *(short8*)&Bs[srow * 40 + scol + 8] = b1;
    __syncthreads();
    short8 af[4], bf[4];
    #pragma unroll
    for (int g = 0; g < 4; ++g) {
      af[g] = *(const short8*)&As[(wm + g * 16 + l16) * 40 + quad * 8];
      bf[g] = *(const short8*)&Bs[(wn + g * 16 + l16) * 40 + quad * 8];
    }
    #pragma unroll
    for (int gm = 0; gm < 4; ++gm)
      #pragma unroll
      for (int gn = 0; gn < 4; ++gn)
        acc[gm][gn] = __builtin_amdgcn_mfma_f32_16x16x32_bf16(
            af[gm], bf[gn], acc[gm][gn], 0, 0, 0);
    __syncthreads();
  }
}

// ============ K projection (bf16 in/out): Kb[b,h,j,e] bf16 ===============
__global__ __launch_bounds__(256) void k_kv_bf(const short* __restrict__ xbf,
                                               const short* __restrict__ wbf,
                                               short* __restrict__ Kb) {
  __shared__ __align__(16) short As[128 * 40];
  __shared__ __align__(16) short Bs[128 * 40];
  const int tid = threadIdx.x;
  const int lane = tid & 63, wv = tid >> 6;
  const int quad = lane >> 4, l16 = lane & 15;
  const int wm = (wv >> 1) * 64, wn = (wv & 1) * 64;
  const int mBase = blockIdx.y * 128, nBase = blockIdx.x * 128;
  const int srow = tid >> 1, scol = (tid & 1) * 16;
  int am = mBase + srow; if (am >= XTOK) am = 0;
  const short* aptr = xbf + (size_t)am * NC + scol;
  const short* bptr = wbf + (size_t)(768 + nBase + srow) * NC + scol;
  floatx4 acc[4][4] = {};
  mfma_loop_bf(aptr, bptr, As, Bs, srow, scol, wm, wn, quad, l16, acc);
  #pragma unroll
  for (int gm = 0; gm < 4; ++gm) {
    #pragma unroll
    for (int gn = 0; gn < 4; ++gn) {
      #pragma unroll
      for (int r = 0; r < 4; ++r) {
        int m = mBase + wm + gm * 16 + quad * 4 + r;
        if (m >= XTOK) continue;
        int n = nBase + wn + gn * 16 + l16;
        int bb = m / NTOK, jt = m % NTOK;
        int hh = n >> 6, e = n & 63;
        Kb[(((size_t)(bb * NH + hh)) * NTOK + jt) * HD + e] = f2bf(acc[gm][gn][r]);
      }
    }
  }
}

// ============ gathered Q projection (bf16 in/out): Qs[m,n] bf16 ==========
__global__ __launch_bounds__(256) void k_qs_bf(const short* __restrict__ xbf,
                                               const short* __restrict__ wbf,
                                               const int* __restrict__ uniq,
                                               short* __restrict__ Qs) {
  __shared__ __align__(16) short As[128 * 40];
  __shared__ __align__(16) short Bs[128 * 40];
  const int tid = threadIdx.x;
  const int lane = tid & 63, wv = tid >> 6;
  const int quad = lane >> 4, l16 = lane & 15;
  const int wm = (wv >> 1) * 64, wn = (wv & 1) * 64;
  const int mBase = blockIdx.y * 128, nBase = blockIdx.x * 128;
  const int srow = tid >> 1, scol = (tid & 1) * 16;
  int am = mBase + srow;
  const short* aptr;
  if (am < MOUT) {
    int bb = am / SP1, ii = am % SP1;
    int tok = uniq[bb * SP1 + ii];
    aptr = xbf + ((size_t)bb * NTOK + tok) * NC + scol;
  } else {
    aptr = xbf + scol;
  }
  const short* bptr = wbf + (size_t)(nBase + srow) * NC + scol;
  floatx4 acc[4][4] = {};
  mfma_loop_bf(aptr, bptr, As, Bs, srow, scol, wm, wn, quad, l16, acc);
  #pragma unroll
  for (int gm = 0; gm < 4; ++gm) {
    #pragma unroll
    for (int gn = 0; gn < 4; ++gn) {
      #pragma unroll
      for (int r = 0; r < 4; ++r) {
        int m = mBase + wm + gm * 16 + quad * 4 + r;
        if (m >= MOUT) continue;
        int n = nBase + wn + gn * 16 + l16;
        Qs[(size_t)m * NC + n] = f2bf(acc[gm][gn][r]);
      }
    }
  }
}

// ============ output projection + bias (bf16 in, fp32 out) ===============
__global__ __launch_bounds__(256) void k_proj_bf(const short* __restrict__ A,
                                                 const short* __restrict__ wpbf,
                                                 const float* __restrict__ bias,
                                                 float* __restrict__ out) {
  __shared__ __align__(16) short As[128 * 40];
  __shared__ __align__(16) short Bs[128 * 40];
  const int tid = threadIdx.x;
  const int lane = tid & 63, wv = tid >> 6;
  const int quad = lane >> 4, l16 = lane & 15;
  const int wm = (wv >> 1) * 64, wn = (wv & 1) * 64;
  const int mBase = blockIdx.y * 128, nBase = blockIdx.x * 128;
  const int srow = tid >> 1, scol = (tid & 1) * 16;
  int am = mBase + srow; if (am >= MOUT) am = 0;
  const short* aptr = A + (size_t)am * NC + scol;
  const short* bptr = wpbf + (size_t)(nBase + srow) * NC + scol;
  floatx4 acc[4][4] = {};
  mfma_loop_bf(aptr, bptr, As, Bs, srow, scol, wm, wn, quad, l16, acc);
  #pragma unroll
  for (int gm = 0; gm < 4; ++gm) {
    #pragma unroll
    for (int gn = 0; gn < 4; ++gn) {
      #pragma unroll
      for (int r = 0; r < 4; ++r) {
        int m = mBase + wm + gm * 16 + quad * 4 + r;
        if (m >= MOUT) continue;
        int n = nBase + wn + gn * 16 + l16;
        out[(size_t)m * NC + n] = acc[gm][gn][r] + bias[n];
      }
    }
  }
}

// ------- fp64 tiled: logits0[b,h,j] = 0.125 * x[b,j,:].wq0[b,h,:] ---------
__global__ __launch_bounds__(256) void k_logits0b(const float* __restrict__ x,
                                                  const double* __restrict__ wq0,
                                                  double* __restrict__ logits0) {
  const int jt = blockIdx.x;
  const int b = blockIdx.y;
  const int tid = threadIdx.x;
  __shared__ float xs[64][129];
  __shared__ double ws[12][128];
  const int j = tid & 63;
  const int hg = tid >> 6;
  double acc[3] = {0.0, 0.0, 0.0};
  for (int ct = 0; ct < 6; ++ct) {
    const int r = tid >> 2, cg = (tid & 3) * 32;
    int jg = jt * 64 + r; if (jg > 576) jg = 576;
    const float* xr = x + ((size_t)b * NTOK + jg) * NC + ct * 128 + cg;
    #pragma unroll
    for (int k = 0; k < 32; k += 4) {
      float4 v = *(const float4*)(xr + k);
      xs[r][cg + k + 0] = v.x; xs[r][cg + k + 1] = v.y;
      xs[r][cg + k + 2] = v.z; xs[r][cg + k + 3] = v.w;
    }
    for (int t = tid; t < 12 * 128; t += 256) {
      int hh = t >> 7, cc = t & 127;
      ws[hh][cc] = wq0[((size_t)b * NH + hh) * NC + ct * 128 + cc];
    }
    __syncthreads();
    #pragma unroll 4
    for (int c = 0; c < 128; ++c) {
      double xv = (double)xs[j][c];
      acc[0] += xv * ws[hg * 3 + 0][c];
      acc[1] += xv * ws[hg * 3 + 1][c];
      acc[2] += xv * ws[hg * 3 + 2][c];
    }
    __syncthreads();
  }
  const int jg = jt * 64 + j;
  if (jg < NTOK) {
    #pragma unroll
    for (int k = 0; k < 3; ++k)
      logits0[((size_t)b * NH + (hg * 3 + k)) * NTOK + jg] = 0.125 * acc[k];
  }
}

// ===== per-(b,h) significance contribution (12x parallel) ================
__global__ __launch_bounds__(256) void k_sigh(const double* __restrict__ logits0,
                                              const double* __restrict__ vnorm2,
                                              double* __restrict__ contrib) {
  const int bh = blockIdx.x;
  const int tid = threadIdx.x;
  __shared__ double sred[256];
  const double* lp = logits0 + (size_t)bh * NTOK;
  const double* vn = vnorm2 + (size_t)bh * NTOK;
  double pmax = -1e300;
  for (int j = tid; j < NTOK; j += 256) pmax = fmax(pmax, lp[j]);
  sred[tid] = pmax;
  __syncthreads();
  for (int s = 128; s > 0; s >>= 1) {
    if (tid < s) sred[tid] = fmax(sred[tid], sred[tid + s]);
    __syncthreads();
  }
  double m = sred[0];
  __syncthreads();
  double psum = 0.0;
  for (int j = tid; j < NTOK; j += 256) psum += exp(lp[j] - m);
  sred[tid] = psum;
  __syncthreads();
  for (int s = 128; s > 0; s >>= 1) {
    if (tid < s) sred[tid] += sred[tid + s];
    __syncthreads();
  }
  double denom = sred[0];
  __syncthreads();
  for (int j = tid + 1; j < NTOK; j += 256)
    contrib[(size_t)bh * 576 + (j - 1)] = exp(lp[j] - m) / denom * sqrt(vn[j]);
}

// ---- combine contributions + cdf + sampling + unique (outputs 1,2) -------
__global__ __launch_bounds__(256) void k_sig2(const double* __restrict__ contrib,
                                              int* __restrict__ uniq_ws,
                                              float* __restrict__ out_mask,
                                              float* __restrict__ out_uniq) {
  const int b = blockIdx.x;
  const int tid = threadIdx.x;
  __shared__ double sig[576];
  __shared__ double cdf[576];
  __shared__ double sred[256];
  __shared__ int ids[256];
  __shared__ int flags[NTOK];
  __shared__ int ulist[SP1];
  for (int j = tid; j < 576; j += 256) {
    double s = 0.0;
    #pragma unroll
    for (int h = 0; h < NH; ++h)
      s += contrib[((size_t)(b * NH + h)) * 576 + j];
    sig[j] = s;
  }
  __syncthreads();
  double tsum = 0.0;
  for (int j = tid; j < 576; j += 256) tsum += sig[j];
  sred[tid] = tsum;
  __syncthreads();
  for (int s = 128; s > 0; s >>= 1) {
    if (tid < s) sred[tid] += sred[tid + s];
    __syncthreads();
  }
  double denom2 = sred[0] + 1e-6;
  __syncthreads();
  if (tid == 0) {
    double c = 0.0;
    for (int j = 0; j < 576; ++j) { c += sig[j] / denom2; cdf[j] = c; }
  }
  __syncthreads();
  {
    double step = (2.0 * tid + 1.0) / 512.0;
    double best = 1e300;
    int bj = 0;
    for (int j = 0; j < 576; ++j) {
      double d = fabs(step - cdf[j]);
      if (d < best) { best = d; bj = j; }
    }
    ids[tid] = bj + 1;
  }
  for (int j = tid; j < NTOK; j += 256) flags[j] = 0;
  __syncthreads();
  flags[ids[tid]] = 1;
  __syncthreads();
  if (tid == 0) {
    int cnt = 0;
    ulist[0] = 0;
    for (int j = 1; j < NTOK; ++j)
      if (flags[j]) ulist[++cnt] = j;
    for (int k = cnt + 1; k < SP1; ++k) ulist[k] = 0;
  }
  __syncthreads();
  for (int k = tid; k < SP1; k += 256) {
    int v = ulist[k];
    uniq_ws[b * SP1 + k] = v;
    out_uniq[b * SP1 + k] = (float)v;
    out_mask[b * SP1 + k] = (k == 0 || v != 0) ? 1.0f : 0.0f;
  }
}

// -------- flash-style attention over sampled rows, bf16 MFMA ----------
__global__ __launch_bounds__(256) void k_attn2(const short* __restrict__ Qs,
                                               const short* __restrict__ Kb,
                                               const short* __restrict__ Vb,
                                               short* __restrict__ attnv) {
  const int it = blockIdx.x;
  const int h = blockIdx.y;
  const int b = blockIdx.z;
  const int tid = threadIdx.x;
  const int lane = tid & 63, wv = tid >> 6;
  const int l16 = lane & 15, quad = lane >> 4;
  const int i0 = it * 64;
  __shared__ __align__(16) short Qt[64][72];   // [i][e]
  __shared__ __align__(16) short Kt[64][72];   // [j][e]
  __shared__ __align__(16) short Vt[64][72];   // [e][j]  (transposed)
  __shared__ __align__(16) short Pt[64][72];   // [i][j]
  {
    const int r16 = tid & 15;
    const int e = (tid >> 4) * 4;
    #pragma unroll
    for (int rb = 0; rb < 4; ++rb) {
      int row = rb * 16 + r16;
      int ig = i0 + row; if (ig > 256) ig = 256;
      *(unsigned long long*)&Qt[row][e] =
          *(const unsigned long long*)(Qs + ((size_t)b * SP1 + ig) * NC + h * HD + e);
    }
  }
  float m_i[4], l_i[4];
  floatx4 O[4];
  #pragma unroll
  for (int r = 0; r < 4; ++r) { m_i[r] = -1e30f; l_i[r] = 0.f; }
  #pragma unroll
  for (int g = 0; g < 4; ++g) O[g] = (floatx4){0.f, 0.f, 0.f, 0.f};
  const short* Kh = Kb + ((size_t)(b * NH + h)) * NTOK * HD;
  const short* Vh = Vb + ((size_t)(b * NH + h)) * NTOK * HD;
  const int prow = wv * 16 + l16;            // A-operand row for this lane
  for (int jt = 0; jt < 10; ++jt) {
    {
      const int r16 = tid & 15;
      const int e = (tid >> 4) * 4;
      #pragma unroll
      for (int rb = 0; rb < 4; ++rb) {
        int jr = rb * 16 + r16;
        int jg = jt * 64 + jr; if (jg > 576) jg = 576;
        *(unsigned long long*)&Kt[jr][e] =
            *(const unsigned long long*)(Kh + (size_t)jg * HD + e);
        S4 vv; vv.u = *(const unsigned long long*)(Vh + (size_t)jg * HD + e);
        Vt[e + 0][jr] = vv.s[0]; Vt[e + 1][jr] = vv.s[1];
        Vt[e + 2][jr] = vv.s[2]; Vt[e + 3][jr] = vv.s[3];
      }
    }
    __syncthreads();
    floatx4 s[4];
    #pragma unroll
    for (int g = 0; g < 4; ++g) s[g] = (floatx4){0.f, 0.f, 0.f, 0.f};
    {
      short8 aq0 = *(const short8*)&Qt[prow][quad * 8];
      short8 aq1 = *(const short8*)&Qt[prow][32 + quad * 8];
      #pragma unroll
      for (int g = 0; g < 4; ++g) {
        short8 bk0 = *(const short8*)&Kt[g * 16 + l16][quad * 8];
        short8 bk1 = *(const short8*)&Kt[g * 16 + l16][32 + quad * 8];
        s[g] = __builtin_amdgcn_mfma_f32_16x16x32_bf16(aq0, bk0, s[g], 0, 0, 0);
        s[g] = __builtin_amdgcn_mfma_f32_16x16x32_bf16(aq1, bk1, s[g], 0, 0, 0);
      }
    }
    #pragma unroll
    for (int g = 0; g < 4; ++g) {
      int jg = jt * 64 + g * 16 + l16;
      #pragma unroll
      for (int r = 0; r < 4; ++r) {
        float sv = s[g][r] * 0.125f;
        s[g][r] = (jg >= NTOK) ? -1e30f : sv;
      }
    }
    #pragma unroll
    for (int r = 0; r < 4; ++r) {
      float mr = fmaxf(fmaxf(s[0][r], s[1][r]), fmaxf(s[2][r], s[3][r]));
      #pragma unroll
      for (int off = 1; off < 16; off <<= 1) mr = fmaxf(mr, __shfl_xor(mr, off));
      float mn = fmaxf(m_i[r], mr);
      float alpha = expf(m_i[r] - mn);
      float ps = 0.f;
      #pragma unroll
      for (int g = 0; g < 4; ++g) {
        float p = expf(s[g][r] - mn);
        s[g][r] = p;
        ps += p;
      }
      #pragma unroll
      for (int off = 1; off < 16; off <<= 1) ps += __shfl_xor(ps, off);
      l_i[r] = l_i[r] * alpha + ps;
      m_i[r] = mn;
      #pragma unroll
      for (int g = 0; g < 4; ++g) O[g][r] *= alpha;
    }
    #pragma unroll
    for (int g = 0; g < 4; ++g)
      #pragma unroll
      for (int r = 0; r < 4; ++r)
        Pt[wv * 16 + quad * 4 + r][g * 16 + l16] = f2bf(s[g][r]);
    __syncthreads();
    {
      short8 ap0 = *(const short8*)&Pt[prow][quad * 8];
      short8 ap1 = *(const short8*)&Pt[prow][32 + quad * 8];
      #pragma unroll
      for (int g = 0; g < 4; ++g) {
        short8 bv0 = *(const short8*)&Vt[g * 16 + l16][quad * 8];
        short8 bv1 = *(const short8*)&Vt[g * 16 + l16][32 + quad * 8];
        O[g] = __builtin_amdgcn_mfma_f32_16x16x32_bf16(ap0, bv0, O[g], 0, 0, 0);
        O[g] = __builtin_amdgcn_mfma_f32_16x16x32_bf16(ap1, bv1, O[g], 0, 0, 0);
      }
    }
    __syncthreads();
  }
  #pragma unroll
  for (int r = 0; r < 4; ++r) {
    int i = i0 + wv * 16 + quad * 4 + r;
    if (i >= SP1) continue;
    float inv = 1.0f / l_i[r];
    #pragma unroll
    for (int g = 0; g < 4; ++g)
      attnv[((size_t)b * SP1 + i) * NC + h * HD + g * 16 + l16] = f2bf(O[g][r] * inv);
  }
}

extern "C" void kernel_launch(void* const* d_in, const int* in_sizes, int n_in,
                              void* d_out, int out_size, void* d_ws,
                              size_t ws_size, hipStream_t stream) {
  (void)in_sizes; (void)n_in; (void)out_size; (void)ws_size;
  const float* x = (const float*)d_in[0];
  const float* qkv_w = (const float*)d_in[2];
  const float* proj_w = (const float*)d_in[3];
  const float* proj_b = (const float*)d_in[4];

  char* ws = (char*)d_ws;
  size_t off = 0;
  short* xbf = (short*)(ws + off); off += (size_t)XTOK * NC * 2;
  short* wbf = (short*)(ws + off); off += (size_t)1536 * NC * 2;
  short* wpbf = (short*)(ws + off); off += (size_t)NC * NC * 2;
  short* Kb = (short*)(ws + off); off += (size_t)NB * NH * NTOK * HD * 2;
  short* Vb = (short*)(ws + off); off += (size_t)NB * NH * NTOK * HD * 2;
  short* Qs = (short*)(ws + off); off += (size_t)MOUT * NC * 2;
  short* attnv = (short*)(ws + off); off += (size_t)MOUT * NC * 2;
  double* wq0 = (double*)(ws + off); off += (size_t)NB * NH * NC * 8;
  double* logits0 = (double*)(ws + off); off += (size_t)NB * NH * NTOK * 8;
  double* vnorm2 = (double*)(ws + off); off += (size_t)NB * NH * NTOK * 8;
  double* contrib = (double*)(ws + off); off += (size_t)NB * NH * 576 * 8;
  int* uniq_ws = (int*)(ws + off); off += (size_t)NB * SP1 * 4;

  float* out0 = (float*)d_out;
  float* out_mask = out0 + (size_t)MOUT * NC;
  float* out_uniq = out_mask + (size_t)NB * SP1;

  // 1. merged: V projection/vnorm2 (fp64 MFMA) + bf16 conversion + q0/wq0,
  //    with 128-VGPR cap so vnorm's occupancy is unharmed.
  k_pre<<<9912, 256, 0, stream>>>(x, qkv_w, proj_w, xbf, wbf, wpbf,
                                  Vb, vnorm2, wq0);
  // 2. CLS logits (fp64, tiled)
  k_logits0b<<<dim3(10, NB), 256, 0, stream>>>(x, wq0, logits0);
  // 3. K projection (bf16 in/out)
  k_kv_bf<<<dim3(6, 145), 256, 0, stream>>>(xbf, wbf, Kb);
  // 4. per-(b,h) significance contributions (12x parallel)
  k_sigh<<<NB * NH, 256, 0, stream>>>(logits0, vnorm2, contrib);
  // 5. combine + cdf + sampling + unique (+ outputs 1,2)
  k_sig2<<<NB, 256, 0, stream>>>(contrib, uniq_ws, out_mask, out_uniq);
  // 6. gathered Q projection (bf16 in/out)
  k_qs_bf<<<dim3(6, 65), 256, 0, stream>>>(xbf, wbf, uniq_ws, Qs);
  // 7. flash-style attention over sampled rows (all-bf16 staging)
  k_attn2<<<dim3(5, NH, NB), 256, 0, stream>>>(Qs, Kb, Vb, attnv);
  // 8. output projection (+bias, bf16 in, fp32 out) -> output 0
  k_proj_bf<<<dim3(6, 65), 256, 0, stream>>>(attnv, wpbf, proj_b, out0);
}